// Round 1
// 132.650 us; speedup vs baseline: 1.0024x; 1.0024x over previous
//
#include <hip/hip_runtime.h>

// SimpleEdgeModel round 7: occupancy. R6 counters: edge 58us, MfmaUtil 24%,
// Occupancy 19%, LDS 64KB/block -> 2 blocks/CU = 2 waves/SIMD; MFMA floor is
// ~17.5us so the pipe idles ~70% waiting for lockstep phases.
//
// Changes vs R6:
//   - j-tile per wave 4 -> 2 (32 j-rows/wave); grid 512 -> 1024 blocks
//     (= exactly 4 blocks/CU). LDS 64 -> 32KB/block, so occupancy is
//     VGPR-bound: ~105 regs -> 4 waves/SIMD = 16 waves/CU (2x R6).
//   - gbh j-frags hoisted out of the u (i) loop: independent of i.
//   - bc2/bc3 folded into MFMA acc init (acc = {b,b}) - kills 8 f32 adds
//     per nt iter per layer.
//   - W2T/W3T frag order changed to (nt*4+ks): the 4 ks loads per nt are
//     one 4KB span -> one 64-bit address + imm offsets.
//   - s_setprio(1) around MFMA clusters (waves are barrier-free and
//     phase-staggered -> T5 regime).
//
// out[b,i,j] = Wo.relu(W3^T.relu(W2^T.relu(g_j+bc1-g_i)+bc2)+bc3)+bo
// g = nodeMLP(x)@Wc1.  Per wave: 32 j-rows x 4 i-units; no barriers.

typedef _Float16 half_t;
typedef __attribute__((ext_vector_type(2))) _Float16 f16x2;
typedef __attribute__((ext_vector_type(8))) _Float16 f16x8;
typedef __attribute__((ext_vector_type(4))) float f32x4;

// ws layout:
//   gh  : 1024*128 f16 @ 0        = f16(g)
//   gbh : 1024*128 f16 @ 262144   = f16(g + bc1)
//   W2T : 16384 f16    @ 524288   (frag-packed Wc2, (nt*4+ks) order)
//   W3T : 16384 f16    @ 557056

// ---------------------------------------------------------------------------
// prep: blocks 0..255 node MLP (4 nodes/block); 256..271 weight frag pack.
// Frag (nt,ks), lane L=q*16+c, elem e  <-  Wsrc[32ks+8q+e][16nt+c].
// ---------------------------------------------------------------------------
__global__ __launch_bounds__(256) void prep_kernel(
    const float* __restrict__ x, const float* __restrict__ Wa, const float* __restrict__ ba,
    const float* __restrict__ Wb, const float* __restrict__ bb, const float* __restrict__ Wc1,
    const float* __restrict__ bc1, const float* __restrict__ Wc2, const float* __restrict__ Wc3,
    half_t* __restrict__ gh, half_t* __restrict__ gbh,
    half_t* __restrict__ W2T, half_t* __restrict__ W3T)
{
  const int t = threadIdx.x;
  if (blockIdx.x >= 256) {
    const int bid = blockIdx.x - 256;            // layer(1b) x ntile(3b)
    const int layer = bid >> 3, nt = bid & 7;
    const int ks = t >> 6, L = t & 63, q = L >> 4, cc = L & 15;
    const float* src = layer ? Wc3 : Wc2;
    half_t* dst = layer ? W3T : W2T;
    f16x8 v;
    #pragma unroll
    for (int e = 0; e < 8; e++)
      v[e] = (half_t)src[(32 * ks + 8 * q + e) * 128 + 16 * nt + cc];
    *(f16x8*)(dst + (nt * 4 + ks) * 512 + L * 8) = v;   // ks-frags contiguous per nt
    return;
  }
  __shared__ float sx[64 * 6];
  __shared__ float sh1[128 * 6];
  __shared__ float sh2[128 * 6];
  const int n0 = blockIdx.x * 4;
  const int col = t & 127, hf = t >> 7;

  sx[(t & 63) * 6 + (t >> 6)] = x[(n0 + (t >> 6)) * 64 + (t & 63)];
  __syncthreads();

  float a0 = ba[col], a1 = a0;
  #pragma unroll
  for (int cc = 0; cc < 64; cc++) {
    const float wv = Wa[cc * 128 + col];
    const float2 xv = *(const float2*)(sx + cc * 6 + hf * 2);
    a0 = fmaf(xv.x, wv, a0); a1 = fmaf(xv.y, wv, a1);
  }
  *(float2*)(sh1 + col * 6 + hf * 2) = make_float2(fmaxf(a0, 0.f), fmaxf(a1, 0.f));
  __syncthreads();

  float b0 = bb[col], b1 = b0;
  #pragma unroll
  for (int k = 0; k < 128; k++) {
    const float wv = Wb[k * 128 + col];
    const float2 hv = *(const float2*)(sh1 + k * 6 + hf * 2);
    b0 = fmaf(hv.x, wv, b0); b1 = fmaf(hv.y, wv, b1);
  }
  *(float2*)(sh2 + col * 6 + hf * 2) = make_float2(fmaxf(b0, 0.f), fmaxf(b1, 0.f));
  __syncthreads();

  float c0 = 0.f, c1 = 0.f;
  #pragma unroll
  for (int k = 0; k < 128; k++) {
    const float wv = Wc1[k * 128 + col];
    const float2 hv = *(const float2*)(sh2 + k * 6 + hf * 2);
    c0 = fmaf(hv.x, wv, c0); c1 = fmaf(hv.y, wv, c1);
  }
  const float bv = bc1[col];
  const int r0 = n0 + hf * 2;
  gh [(r0 + 0) * 128 + col] = (half_t)c0;
  gh [(r0 + 1) * 128 + col] = (half_t)c1;
  gbh[(r0 + 0) * 128 + col] = (half_t)(c0 + bv);
  gbh[(r0 + 1) * 128 + col] = (half_t)(c1 + bv);
}

// ---------------------------------------------------------------------------
// edge kernel. 1024 blocks = b(1b) x jq(2b) x ichunk(7b, 4 i each).
// Wave w owns j-rows [jq*128 + w*32, +32).  LDS: 8KB/wave private.
// ---------------------------------------------------------------------------
static __device__ inline f16x8 relu_sub8(f16x8 a, f16x8 b) {
  f16x8 d = a - b;
  const f16x8 z = {};
  return __builtin_elementwise_max(d, z);
}

__global__ __launch_bounds__(256, 4)
void edge_kernel(
    const half_t* __restrict__ gh, const half_t* __restrict__ gbh,
    const half_t* __restrict__ W2T, const half_t* __restrict__ W3T,
    const float* __restrict__ bc2, const float* __restrict__ bc3,
    const float* __restrict__ Wo, const float* __restrict__ bo,
    float* __restrict__ out)
{
  __shared__ half_t sE[4 * 8 * 512];             // 32 KB, 8 KB per wave
  const int t = threadIdx.x, lane = t & 63, w = t >> 6;
  const int c = lane & 15, q = lane >> 4;
  const int bid = blockIdx.x;
  const int b = bid >> 9, jq = (bid >> 7) & 3, ic = bid & 127;
  const int i0 = ic * 4;
  const int j0w = jq * 128 + w * 32;

  half_t* sEw = sE + w * (8 * 512);
  const float bo0 = bo[0];
  // LDS pack address (halfs): ((q>>1)*16+c)*8 + (q&1)*4; +256 halfs when nt odd
  const int packoff = ((q >> 1) * 16 + c) * 8 + (q & 1) * 4;
  const int rdoff = lane * 8;

  // ---- gbh j-frags: independent of i, hoisted out of the u loop (32 regs) --
  f16x8 gj[4][2];
  #pragma unroll
  for (int ks = 0; ks < 4; ks++)
    #pragma unroll
    for (int jt = 0; jt < 2; jt++)
      gj[ks][jt] = *(const f16x8*)(gbh + (size_t)(b * 512 + j0w + jt * 16 + c) * 128 + ks * 32 + q * 8);

  #pragma unroll 1
  for (int u = 0; u < 4; u++) {
    const int i = i0 + u;

    // ---- phase A: e1[ks][jt] in regs (32 VGPRs) ----
    f16x8 e1[4][2];
    {
      f16x8 gih[4];
      #pragma unroll
      for (int ks = 0; ks < 4; ks++)
        gih[ks] = *(const f16x8*)(gh + (size_t)(b * 512 + i) * 128 + ks * 32 + q * 8);
      #pragma unroll
      for (int ks = 0; ks < 4; ks++)
        #pragma unroll
        for (int jt = 0; jt < 2; jt++)
          e1[ks][jt] = relu_sub8(gj[ks][jt], gih[ks]);
    }

    // ---- phase B: layer 2, nt outermost; bias pre-loaded into acc ----
    #pragma unroll 1
    for (int nt = 0; nt < 8; nt++) {
      f16x8 wf[4];
      #pragma unroll
      for (int ks = 0; ks < 4; ks++)
        wf[ks] = *(const f16x8*)(W2T + nt * 2048 + ks * 512 + rdoff);
      const f32x4 b2 = *(const f32x4*)(bc2 + nt * 16 + q * 4);
      f32x4 acc[2] = {b2, b2};
      __builtin_amdgcn_s_setprio(1);
      #pragma unroll
      for (int ks = 0; ks < 4; ks++)
        #pragma unroll
        for (int jt = 0; jt < 2; jt++)
          acc[jt] = __builtin_amdgcn_mfma_f32_16x16x32_f16(wf[ks], e1[ks][jt], acc[jt], 0, 0, 0);
      __builtin_amdgcn_s_setprio(0);
      // pack e2 = relu(acc) -> LDS in layer-3 B-frag order (b64 writes)
      const int po = ((nt >> 1) * 512) + packoff + (nt & 1) * 256;   // ks3 slot base
      #pragma unroll
      for (int jt = 0; jt < 2; jt++) {
        const f32x4 v = acc[jt];
        f16x2 h01, h23;
        h01[0] = (half_t)fmaxf(v[0], 0.f); h01[1] = (half_t)fmaxf(v[1], 0.f);
        h23[0] = (half_t)fmaxf(v[2], 0.f); h23[1] = (half_t)fmaxf(v[3], 0.f);
        uint2 uv;
        uv.x = __builtin_bit_cast(unsigned int, h01);
        uv.y = __builtin_bit_cast(unsigned int, h23);
        *(uint2*)(sEw + jt * 2048 + po) = uv;    // (jt*4+ks3)*512 = jt*2048 + ks3*512
      }
    }

    // ---- phase C: layer 3; be[ks3][jt] from LDS (32 regs, e1 dead) ----
    f16x8 be[4][2];
    #pragma unroll
    for (int ks3 = 0; ks3 < 4; ks3++)
      #pragma unroll
      for (int jt = 0; jt < 2; jt++)
        be[ks3][jt] = *(const f16x8*)(sEw + (jt * 4 + ks3) * 512 + rdoff);

    float p[2] = {0.f, 0.f};
    #pragma unroll 1
    for (int nt = 0; nt < 8; nt++) {
      f16x8 wf[4];
      #pragma unroll
      for (int ks3 = 0; ks3 < 4; ks3++)
        wf[ks3] = *(const f16x8*)(W3T + nt * 2048 + ks3 * 512 + rdoff);
      const f32x4 b3 = *(const f32x4*)(bc3 + nt * 16 + q * 4);
      f32x4 acc[2] = {b3, b3};
      __builtin_amdgcn_s_setprio(1);
      #pragma unroll
      for (int ks3 = 0; ks3 < 4; ks3++)
        #pragma unroll
        for (int jt = 0; jt < 2; jt++)
          acc[jt] = __builtin_amdgcn_mfma_f32_16x16x32_f16(wf[ks3], be[ks3][jt], acc[jt], 0, 0, 0);
      __builtin_amdgcn_s_setprio(0);
      const f32x4 wo = *(const f32x4*)(Wo + nt * 16 + q * 4);
      #pragma unroll
      for (int jt = 0; jt < 2; jt++)
        #pragma unroll
        for (int r = 0; r < 4; r++)
          p[jt] = fmaf(fmaxf(acc[jt][r], 0.f), wo[r], p[jt]);
    }

    // ---- epilogue: reduce over q (rows n3 split across q), store ----
    #pragma unroll
    for (int jt = 0; jt < 2; jt++) {
      p[jt] += __shfl_xor(p[jt], 16, 64);
      p[jt] += __shfl_xor(p[jt], 32, 64);
    }
    if (q == 0) {
      const size_t base = ((size_t)(b * 512 + i)) * 512 + j0w;
      #pragma unroll
      for (int jt = 0; jt < 2; jt++)
        out[base + jt * 16 + c] = p[jt] + bo0;
    }
  }
}

// ---------------------------------------------------------------------------
extern "C" void kernel_launch(void* const* d_in, const int* in_sizes, int n_in,
                              void* d_out, int out_size, void* d_ws, size_t ws_size,
                              hipStream_t stream)
{
  const float* x   = (const float*)d_in[0];
  const float* Wa  = (const float*)d_in[1];
  const float* ba  = (const float*)d_in[2];
  const float* Wb  = (const float*)d_in[3];
  const float* bb  = (const float*)d_in[4];
  const float* Wc1 = (const float*)d_in[5];
  const float* bc1 = (const float*)d_in[6];
  const float* Wc2 = (const float*)d_in[7];
  const float* bc2 = (const float*)d_in[8];
  const float* Wc3 = (const float*)d_in[9];
  const float* bc3 = (const float*)d_in[10];
  const float* Wo  = (const float*)d_in[11];
  const float* bo  = (const float*)d_in[12];
  float* out = (float*)d_out;

  char* ws = (char*)d_ws;
  half_t* gh  = (half_t*)ws;                      // 256 KB
  half_t* gbh = (half_t*)(ws + 262144);           // 256 KB
  half_t* W2T = (half_t*)(ws + 524288);           // 32 KB
  half_t* W3T = (half_t*)(ws + 557056);           // 32 KB

  prep_kernel<<<272, 256, 0, stream>>>(x, Wa, ba, Wb, bb, Wc1, bc1, Wc2, Wc3,
                                       gh, gbh, W2T, W3T);
  edge_kernel<<<1024, 256, 0, stream>>>(gh, gbh, W2T, W3T, bc2, bc3, Wo, bo, out);
}

// Round 2
// 118.717 us; speedup vs baseline: 1.1200x; 1.1174x over previous
//
#include <hip/hip_runtime.h>

// SimpleEdgeModel round 8: weights -> LDS. R7 post-mortem: doubling occupancy
// changed nothing (MfmaUtil 23%, 59us) because the CU's L1 path is saturated:
// every nt-iter pulls 5KB of weight/bias frags through L1 for 8 MFMAs
// (~48B/cy per CU vs ~64B/cy service).  Fix: stage W2T/W3T (64KB) + biases
// (1.5KB) in LDS once per block; weight frags now come from the separate
// 128B/cy LDS pipe.  512-thread blocks (8 waves) so weights+8KB/wave handoff
// fit: LDS = 132.6KB, 1 block/CU, 2 waves/SIMD.  DS-pipe demand (~336cy per
// CU-nt) ~ MFMA demand (~310cy per SIMD-nt) -> MfmaUtil should reach 55-75%.
// Biases in LDS (broadcast reads) to avoid runtime-indexed reg arrays
// (scratch, rule #20) and keep VGPR low; nt loops fully unrolled so the
// scheduler pipelines ds_reads under MFMA inside the 256-reg budget.
//
// out[b,i,j] = Wo.relu(W3^T.relu(W2^T.relu(g_j+bc1-g_i)+bc2)+bc3)+bo
// g = nodeMLP(x)@Wc1.  Per wave: 32 j-rows x 4 i-units; no barriers in loop.

typedef _Float16 half_t;
typedef __attribute__((ext_vector_type(2))) _Float16 f16x2;
typedef __attribute__((ext_vector_type(8))) _Float16 f16x8;
typedef __attribute__((ext_vector_type(4))) float f32x4;

// ws layout:
//   gh  : 1024*128 f16 @ 0        = f16(g)
//   gbh : 1024*128 f16 @ 262144   = f16(g + bc1)
//   W2T : 16384 f16    @ 524288   (frag-packed Wc2, (nt*4+ks) order)
//   W3T : 16384 f16    @ 557056

// ---------------------------------------------------------------------------
// prep: blocks 0..255 node MLP (4 nodes/block); 256..271 weight frag pack.
// Frag (nt,ks), lane L=q*16+c, elem e  <-  Wsrc[32ks+8q+e][16nt+c].
// ---------------------------------------------------------------------------
__global__ __launch_bounds__(256) void prep_kernel(
    const float* __restrict__ x, const float* __restrict__ Wa, const float* __restrict__ ba,
    const float* __restrict__ Wb, const float* __restrict__ bb, const float* __restrict__ Wc1,
    const float* __restrict__ bc1, const float* __restrict__ Wc2, const float* __restrict__ Wc3,
    half_t* __restrict__ gh, half_t* __restrict__ gbh,
    half_t* __restrict__ W2T, half_t* __restrict__ W3T)
{
  const int t = threadIdx.x;
  if (blockIdx.x >= 256) {
    const int bid = blockIdx.x - 256;            // layer(1b) x ntile(3b)
    const int layer = bid >> 3, nt = bid & 7;
    const int ks = t >> 6, L = t & 63, q = L >> 4, cc = L & 15;
    const float* src = layer ? Wc3 : Wc2;
    half_t* dst = layer ? W3T : W2T;
    f16x8 v;
    #pragma unroll
    for (int e = 0; e < 8; e++)
      v[e] = (half_t)src[(32 * ks + 8 * q + e) * 128 + 16 * nt + cc];
    *(f16x8*)(dst + (nt * 4 + ks) * 512 + L * 8) = v;   // ks-frags contiguous per nt
    return;
  }
  __shared__ float sx[64 * 6];
  __shared__ float sh1[128 * 6];
  __shared__ float sh2[128 * 6];
  const int n0 = blockIdx.x * 4;
  const int col = t & 127, hf = t >> 7;

  sx[(t & 63) * 6 + (t >> 6)] = x[(n0 + (t >> 6)) * 64 + (t & 63)];
  __syncthreads();

  float a0 = ba[col], a1 = a0;
  #pragma unroll
  for (int cc = 0; cc < 64; cc++) {
    const float wv = Wa[cc * 128 + col];
    const float2 xv = *(const float2*)(sx + cc * 6 + hf * 2);
    a0 = fmaf(xv.x, wv, a0); a1 = fmaf(xv.y, wv, a1);
  }
  *(float2*)(sh1 + col * 6 + hf * 2) = make_float2(fmaxf(a0, 0.f), fmaxf(a1, 0.f));
  __syncthreads();

  float b0 = bb[col], b1 = b0;
  #pragma unroll
  for (int k = 0; k < 128; k++) {
    const float wv = Wb[k * 128 + col];
    const float2 hv = *(const float2*)(sh1 + k * 6 + hf * 2);
    b0 = fmaf(hv.x, wv, b0); b1 = fmaf(hv.y, wv, b1);
  }
  *(float2*)(sh2 + col * 6 + hf * 2) = make_float2(fmaxf(b0, 0.f), fmaxf(b1, 0.f));
  __syncthreads();

  float c0 = 0.f, c1 = 0.f;
  #pragma unroll
  for (int k = 0; k < 128; k++) {
    const float wv = Wc1[k * 128 + col];
    const float2 hv = *(const float2*)(sh2 + k * 6 + hf * 2);
    c0 = fmaf(hv.x, wv, c0); c1 = fmaf(hv.y, wv, c1);
  }
  const float bv = bc1[col];
  const int r0 = n0 + hf * 2;
  gh [(r0 + 0) * 128 + col] = (half_t)c0;
  gh [(r0 + 1) * 128 + col] = (half_t)c1;
  gbh[(r0 + 0) * 128 + col] = (half_t)(c0 + bv);
  gbh[(r0 + 1) * 128 + col] = (half_t)(c1 + bv);
}

// ---------------------------------------------------------------------------
// edge kernel. 512 blocks x 512 threads = b(1b) x jhalf(1b) x ichunk(7b).
// Wave w (0..7) owns j-rows [jhalf*256 + w*32, +32).  LDS:
//   sW2/sW3 64KB weights (block-shared), sBf 1.5KB biases, sE 8KB/wave e2.
// ---------------------------------------------------------------------------
static __device__ inline f16x8 relu_sub8(f16x8 a, f16x8 b) {
  f16x8 d = a - b;
  const f16x8 z = {};
  return __builtin_elementwise_max(d, z);
}

__global__ __launch_bounds__(512, 2)
void edge_kernel(
    const half_t* __restrict__ gh, const half_t* __restrict__ gbh,
    const half_t* __restrict__ W2T, const half_t* __restrict__ W3T,
    const float* __restrict__ bc2, const float* __restrict__ bc3,
    const float* __restrict__ Wo, const float* __restrict__ bo,
    float* __restrict__ out)
{
  __shared__ __align__(16) half_t sW2[16384];    // 32 KB
  __shared__ __align__(16) half_t sW3[16384];    // 32 KB
  __shared__ __align__(16) float  sBf[384];      // bc2 | bc3 | Wo  (1.5 KB)
  __shared__ __align__(16) half_t sE[8 * 4096];  // 64 KB, 8 KB per wave

  const int t = threadIdx.x, lane = t & 63, w = t >> 6;
  const int c = lane & 15, q = lane >> 4;
  const int bid = blockIdx.x;
  const int b = bid >> 8, jh = (bid >> 7) & 1, ic = bid & 127;
  const int i0 = ic * 4;
  const int j0w = jh * 256 + w * 32;

  // ---- stage weights + biases into LDS (once per block) ----
  #pragma unroll
  for (int k = 0; k < 4; k++) {
    const int off = (k * 512 + t) * 8;
    *(f16x8*)(sW2 + off) = *(const f16x8*)(W2T + off);
    *(f16x8*)(sW3 + off) = *(const f16x8*)(W3T + off);
  }
  if (t < 384) sBf[t] = (t < 128) ? bc2[t] : ((t < 256) ? bc3[t - 128] : Wo[t - 256]);
  __syncthreads();

  half_t* sEw = sE + w * 4096;
  const float bo0 = bo[0];
  // LDS pack address (halfs): ((q>>1)*16+c)*8 + (q&1)*4; +256 halfs when nt odd
  const int packoff = ((q >> 1) * 16 + c) * 8 + (q & 1) * 4;
  const int rdoff = lane * 8;

  // ---- gbh j-frags: independent of i, hoisted (32 VGPRs) ----
  f16x8 gj[4][2];
  #pragma unroll
  for (int ks = 0; ks < 4; ks++)
    #pragma unroll
    for (int jt = 0; jt < 2; jt++)
      gj[ks][jt] = *(const f16x8*)(gbh + (size_t)(b * 512 + j0w + jt * 16 + c) * 128 + ks * 32 + q * 8);

  #pragma unroll 1
  for (int u = 0; u < 4; u++) {
    const int i = i0 + u;

    // ---- phase A: e1[ks][jt] in regs (32 VGPRs) ----
    f16x8 e1[4][2];
    {
      f16x8 gih[4];
      #pragma unroll
      for (int ks = 0; ks < 4; ks++)
        gih[ks] = *(const f16x8*)(gh + (size_t)(b * 512 + i) * 128 + ks * 32 + q * 8);
      #pragma unroll
      for (int ks = 0; ks < 4; ks++)
        #pragma unroll
        for (int jt = 0; jt < 2; jt++)
          e1[ks][jt] = relu_sub8(gj[ks][jt], gih[ks]);
    }

    // ---- phase B: layer 2, weights from LDS, bias in acc init ----
    #pragma unroll
    for (int nt = 0; nt < 8; nt++) {
      f16x8 wf[4];
      #pragma unroll
      for (int ks = 0; ks < 4; ks++)
        wf[ks] = *(const f16x8*)(sW2 + nt * 2048 + ks * 512 + rdoff);
      const f32x4 b2 = *(const f32x4*)(sBf + nt * 16 + q * 4);
      f32x4 acc[2] = {b2, b2};
      __builtin_amdgcn_s_setprio(1);
      #pragma unroll
      for (int ks = 0; ks < 4; ks++)
        #pragma unroll
        for (int jt = 0; jt < 2; jt++)
          acc[jt] = __builtin_amdgcn_mfma_f32_16x16x32_f16(wf[ks], e1[ks][jt], acc[jt], 0, 0, 0);
      __builtin_amdgcn_s_setprio(0);
      // pack e2 = relu(acc) -> LDS in layer-3 B-frag order (b64 writes)
      const int po = ((nt >> 1) * 512) + packoff + (nt & 1) * 256;   // ks3 slot base
      #pragma unroll
      for (int jt = 0; jt < 2; jt++) {
        const f32x4 v = acc[jt];
        f16x2 h01, h23;
        h01[0] = (half_t)fmaxf(v[0], 0.f); h01[1] = (half_t)fmaxf(v[1], 0.f);
        h23[0] = (half_t)fmaxf(v[2], 0.f); h23[1] = (half_t)fmaxf(v[3], 0.f);
        uint2 uv;
        uv.x = __builtin_bit_cast(unsigned int, h01);
        uv.y = __builtin_bit_cast(unsigned int, h23);
        *(uint2*)(sEw + jt * 2048 + po) = uv;    // (jt*4+ks3)*512 = jt*2048 + ks3*512
      }
    }

    // ---- phase C: layer 3; be[ks3][jt] from LDS (32 regs, e1 dead) ----
    f16x8 be[4][2];
    #pragma unroll
    for (int ks3 = 0; ks3 < 4; ks3++)
      #pragma unroll
      for (int jt = 0; jt < 2; jt++)
        be[ks3][jt] = *(const f16x8*)(sEw + (jt * 4 + ks3) * 512 + rdoff);

    float p[2] = {0.f, 0.f};
    #pragma unroll
    for (int nt = 0; nt < 8; nt++) {
      f16x8 wf[4];
      #pragma unroll
      for (int ks3 = 0; ks3 < 4; ks3++)
        wf[ks3] = *(const f16x8*)(sW3 + nt * 2048 + ks3 * 512 + rdoff);
      const f32x4 b3 = *(const f32x4*)(sBf + 128 + nt * 16 + q * 4);
      f32x4 acc[2] = {b3, b3};
      __builtin_amdgcn_s_setprio(1);
      #pragma unroll
      for (int ks3 = 0; ks3 < 4; ks3++)
        #pragma unroll
        for (int jt = 0; jt < 2; jt++)
          acc[jt] = __builtin_amdgcn_mfma_f32_16x16x32_f16(wf[ks3], be[ks3][jt], acc[jt], 0, 0, 0);
      __builtin_amdgcn_s_setprio(0);
      const f32x4 wo = *(const f32x4*)(sBf + 256 + nt * 16 + q * 4);
      #pragma unroll
      for (int jt = 0; jt < 2; jt++)
        #pragma unroll
        for (int r = 0; r < 4; r++)
          p[jt] = fmaf(fmaxf(acc[jt][r], 0.f), wo[r], p[jt]);
    }

    // ---- epilogue: reduce over q (rows n3 split across q), store ----
    #pragma unroll
    for (int jt = 0; jt < 2; jt++) {
      p[jt] += __shfl_xor(p[jt], 16, 64);
      p[jt] += __shfl_xor(p[jt], 32, 64);
    }
    if (q == 0) {
      const size_t base = ((size_t)(b * 512 + i)) * 512 + j0w;
      #pragma unroll
      for (int jt = 0; jt < 2; jt++)
        out[base + jt * 16 + c] = p[jt] + bo0;
    }
  }
}

// ---------------------------------------------------------------------------
extern "C" void kernel_launch(void* const* d_in, const int* in_sizes, int n_in,
                              void* d_out, int out_size, void* d_ws, size_t ws_size,
                              hipStream_t stream)
{
  const float* x   = (const float*)d_in[0];
  const float* Wa  = (const float*)d_in[1];
  const float* ba  = (const float*)d_in[2];
  const float* Wb  = (const float*)d_in[3];
  const float* bb  = (const float*)d_in[4];
  const float* Wc1 = (const float*)d_in[5];
  const float* bc1 = (const float*)d_in[6];
  const float* Wc2 = (const float*)d_in[7];
  const float* bc2 = (const float*)d_in[8];
  const float* Wc3 = (const float*)d_in[9];
  const float* bc3 = (const float*)d_in[10];
  const float* Wo  = (const float*)d_in[11];
  const float* bo  = (const float*)d_in[12];
  float* out = (float*)d_out;

  char* ws = (char*)d_ws;
  half_t* gh  = (half_t*)ws;                      // 256 KB
  half_t* gbh = (half_t*)(ws + 262144);           // 256 KB
  half_t* W2T = (half_t*)(ws + 524288);           // 32 KB
  half_t* W3T = (half_t*)(ws + 557056);           // 32 KB

  prep_kernel<<<272, 256, 0, stream>>>(x, Wa, ba, Wb, bb, Wc1, bc1, Wc2, Wc3,
                                       gh, gbh, W2T, W3T);
  edge_kernel<<<512, 512, 0, stream>>>(gh, gbh, W2T, W3T, bc2, bc3, Wo, bo, out);
}